// Round 13
// baseline (5157.750 us; speedup 1.0000x reference)
//
#include <hip/hip_runtime.h>
#include <math.h>

#define CDIM 256
#define HDIM 512
#define KCLS 20
#define MAXSEG 8
#define TILE_R 32
#define NTHR 512
#define GRIDA 2048
#define F4_TILE (TILE_R * CDIM / 4)   // 2048 fp32-float4 per tile
#define F4_THR (F4_TILE / NTHR)       // 4 float4 per thread

typedef __attribute__((ext_vector_type(8))) short bf16x8;
typedef __attribute__((ext_vector_type(4))) float f32x4;

// fp32 -> bf16 round-to-nearest-even (finite inputs)
__device__ __forceinline__ unsigned short f2bf(float x) {
  unsigned u = __float_as_uint(x);
  unsigned r = u + 0x7FFFu + ((u >> 16) & 1u);
  return (unsigned short)(r >> 16);
}
__device__ __forceinline__ unsigned pk2(float a, float b) {
  return (unsigned)f2bf(a) | ((unsigned)f2bf(b) << 16);
}

// Raw barrier: order LDS (lgkmcnt) but leave global loads (vmcnt) IN FLIGHT.
#define BARRIER_LDS_ONLY()                                   \
  do {                                                       \
    asm volatile("s_waitcnt lgkmcnt(0)" ::: "memory");       \
    __builtin_amdgcn_s_barrier();                            \
    __builtin_amdgcn_sched_barrier(0);                       \
  } while (0)

// ---------------------------------------------------------------------------
// Pass A: single read of feat.  MFMA head + bf16 tile (R12) with R12's three
// measured defects fixed:
//   1) staging loads coalesced per-instruction (i*NTHR+t, R8's pattern);
//      bf16 pack in regs, 4x ds_write_b64 at 8B-granule XOR swizzle
//      phys8 = col8 ^ ((row&7)<<1)  (== 16B granule g ^ (row&7) for readers).
//   2) colsum reads are per-lane 16B uint4 granules (8 cols/lane) - floor.
//   3) grid 2048 + W_head B-frags served from a 16KB LDS copy (saves 32
//      VGPRs) -> 3-4 blocks/CU of TLP (the R6->R8 scaling evidence).
// Waves 0-3: one 16x16 MFMA unit (mt=wv&1 rows, nt=wv>>1 cols);
//            8 x { ds_read A, ds_read B(wlds), mfma_f32_16x16x32_bf16 }.
// Waves 4-7: colsum of an 8-row band; lane = (half h, granule g=lane&31),
//            4 rows x uint4; fp32 accumulate; flush-on-seg-change atomics.
// ---------------------------------------------------------------------------
__global__ __launch_bounds__(NTHR, 6) void fused_pool_head_kernel(
    const float* __restrict__ feat, const int* __restrict__ offset,
    const float* __restrict__ W_head, const float* __restrict__ b_head,
    float* __restrict__ sums, float* __restrict__ out, int n, int nseg) {
  __shared__ char tile[TILE_R * CDIM * 2];  // 16 KB bf16 feat tile
  __shared__ char wlds[32 * CDIM * 2];      // 16 KB bf16 W_head (rows 20-31 =0)
  int t = threadIdx.x;
  int lane = t & 63;
  int wv = t >> 6;

  int ntiles = (n + TILE_R - 1) / TILE_R;
  int nb = (int)gridDim.x;
  int t0 = (int)blockIdx.x;

  int off[MAXSEG];
#pragma unroll
  for (int q = 0; q < MAXSEG; ++q) off[q] = (q < nseg) ? offset[q] : 0x7fffffff;

  // ---- build W_lds (once): [32][256] bf16, swizzled like the tile ----
#pragma unroll
  for (int i = 0; i < 4; ++i) {
    int w8 = i * NTHR + t;            // 8B granule index, 0..2047
    int row = w8 >> 6, col8 = w8 & 63;
    uint2 v;
    if (row < KCLS) {
      float4 w = *(const float4*)(W_head + (size_t)row * CDIM + col8 * 4);
      v.x = pk2(w.x, w.y);
      v.y = pk2(w.z, w.w);
    } else {
      v.x = 0u; v.y = 0u;
    }
    *(uint2*)(wlds + row * 512 + (col8 ^ ((row & 7) << 1)) * 8) = v;
  }

  // ---- MFMA setup (waves 0-3) ----
  int mt = wv & 1, nt = wv >> 1;
  int arow = mt * 16 + (lane & 15);
  int brow = nt * 16 + (lane & 15);
  int kg = lane >> 4;
  int ocol = nt * 16 + (lane & 15);
  float bh = (wv < 4 && ocol < KCLS) ? b_head[ocol] : 0.f;

  // ---- colsum state (waves 4-7): lane owns cols 8g..8g+7, 4-row slice ----
  int h = lane >> 5, g = lane & 31;
  f32x4 ca0 = {0.f, 0.f, 0.f, 0.f}, ca1 = {0.f, 0.f, 0.f, 0.f};
  int cur_seg = -1;

  const float4* src = (const float4*)feat;
  long lim = (long)n * (CDIM / 4);
  float4 stgA[F4_THR], stgB[F4_THR];

  auto flush = [&]() {
    if (cur_seg >= 0) {
      float* d = &sums[cur_seg * CDIM + g * 8];
      atomicAdd(d + 0, ca0[0]); atomicAdd(d + 1, ca0[1]);
      atomicAdd(d + 2, ca0[2]); atomicAdd(d + 3, ca0[3]);
      atomicAdd(d + 4, ca1[0]); atomicAdd(d + 5, ca1[1]);
      atomicAdd(d + 6, ca1[2]); atomicAdd(d + 7, ca1[3]);
      ca0 = (f32x4){0.f, 0.f, 0.f, 0.f};
      ca1 = (f32x4){0.f, 0.f, 0.f, 0.f};
    }
  };

  auto issue = [&](float4* stg, int tl) {
    long base = (long)tl * F4_TILE;
    if (base + F4_TILE <= lim) {
#pragma unroll
      for (int i = 0; i < F4_THR; ++i) stg[i] = src[base + i * NTHR + t];
    } else {
#pragma unroll
      for (int i = 0; i < F4_THR; ++i) {
        long idx = base + i * NTHR + t;
        stg[i] = (idx < lim) ? src[idx] : make_float4(0.f, 0.f, 0.f, 0.f);
      }
    }
  };

  auto dswrite = [&](const float4* stg) {
#pragma unroll
    for (int i = 0; i < F4_THR; ++i) {
      float4 v = stg[i];
      int g8 = i * NTHR + t;
      int row = g8 >> 6, col8 = g8 & 63;
      uint2 w;
      w.x = pk2(v.x, v.y);
      w.y = pk2(v.z, v.w);
      *(uint2*)(tile + row * 512 + (col8 ^ ((row & 7) << 1)) * 8) = w;
    }
  };

  auto unpack_acc = [&](uint4 u) {
    ca0[0] += __uint_as_float(u.x << 16);
    ca0[1] += __uint_as_float(u.x & 0xffff0000u);
    ca0[2] += __uint_as_float(u.y << 16);
    ca0[3] += __uint_as_float(u.y & 0xffff0000u);
    ca1[0] += __uint_as_float(u.z << 16);
    ca1[1] += __uint_as_float(u.z & 0xffff0000u);
    ca1[2] += __uint_as_float(u.w << 16);
    ca1[3] += __uint_as_float(u.w & 0xffff0000u);
  };

  auto compute = [&](int tl) {
    long r0 = (long)tl * TILE_R;
    int rows = (int)(((long)n - r0) < TILE_R ? ((long)n - r0) : TILE_R);

    if (wv >= 4) {
      // ---- colsum: my 4-row slice of the band ----
      int rlo = (wv - 4) * 8 + h * 4, rhi = rlo + 4;
      if (rhi > rows) rhi = rows;
      if (rlo < rhi) {
        long ra = r0 + rlo, rb = r0 + rhi - 1;
        int s0 = 0, s1 = 0;
#pragma unroll
        for (int q = 0; q < MAXSEG - 1; ++q) {
          s0 += (ra >= off[q]) ? 1 : 0;
          s1 += (rb >= off[q]) ? 1 : 0;
        }
        if (s0 == s1) {
          if (s0 != cur_seg) { flush(); cur_seg = s0; }
#pragma unroll
          for (int rr = rlo; rr < rhi; ++rr)
            unpack_acc(*(const uint4*)(tile + rr * 512 + ((g ^ (rr & 7)) * 16)));
        } else {
          for (int rr = rlo; rr < rhi; ++rr) {
            long r = r0 + rr;
            int s = 0;
#pragma unroll
            for (int q = 0; q < MAXSEG - 1; ++q) s += (r >= off[q]) ? 1 : 0;
            if (s != cur_seg) { flush(); cur_seg = s; }
            unpack_acc(*(const uint4*)(tile + rr * 512 + ((g ^ (rr & 7)) * 16)));
          }
        }
      }
    } else {
      // ---- MFMA head: one 16x16 output unit per wave, B from wlds ----
      f32x4 acc = {0.f, 0.f, 0.f, 0.f};
#pragma unroll
      for (int ks = 0; ks < 8; ++ks) {
        int gk = ks * 4 + kg;
        bf16x8 a = *(const bf16x8*)(tile + arow * 512 + ((gk ^ (arow & 7)) * 16));
        bf16x8 b = *(const bf16x8*)(wlds + brow * 512 + ((gk ^ (brow & 7)) * 16));
        acc = __builtin_amdgcn_mfma_f32_16x16x32_bf16(a, b, acc, 0, 0, 0);
      }
      if (ocol < KCLS) {
#pragma unroll
        for (int j = 0; j < 4; ++j) {
          int rloc = mt * 16 + kg * 4 + j;
          if (rloc < rows)
            out[(r0 + rloc) * KCLS + ocol] = acc[j] + bh;
        }
      }
    }
  };

  if (t0 < ntiles) {
    // ---- prologue: stage t0 and t0+nb; write t0 into LDS ----
    issue(stgA, t0);
    issue(stgB, t0 + nb < ntiles ? t0 + nb : t0);
    dswrite(stgA);                 // auto vmcnt wait for stgA only
    BARRIER_LDS_ONLY();            // also covers wlds build

    for (int tl = t0; tl < ntiles; tl += 2 * nb) {
      int tA2 = tl + 2 * nb;
      if (tA2 < ntiles) issue(stgA, tA2);   // in flight across this round
      compute(tl);
      BARRIER_LDS_ONLY();                    // readers done (no vmcnt drain)
      int tB = tl + nb;
      if (tB < ntiles) {
        dswrite(stgB);                       // waits stgB loads only
        BARRIER_LDS_ONLY();                  // writes visible
        int tB2 = tl + 3 * nb;
        if (tB2 < ntiles) issue(stgB, tB2);
        compute(tB);
        BARRIER_LDS_ONLY();
        if (tA2 < ntiles) {
          dswrite(stgA);
          BARRIER_LDS_ONLY();
        }
      }
    }
    if (wv >= 4) flush();
  }
}

// ---------------------------------------------------------------------------
// L1: h[s][j], wave-task = gate column j; coalesced W_ih float4 rows;
// 3-step shfl_xor reduce within 8-lane seg groups.
// ---------------------------------------------------------------------------
__global__ __launch_bounds__(256) void lstm_h_kernel(
    const float* __restrict__ sums, const int* __restrict__ offset,
    const float* __restrict__ W_ih, const float* __restrict__ b_ih,
    const float* __restrict__ b_hh, float* __restrict__ h, int nseg) {
  __shared__ float pooled[MAXSEG * CDIM];
  int t = threadIdx.x;
  {
    int prev = 0;
    for (int s = 0; s < MAXSEG; ++s) {
      int cur = (s < nseg) ? offset[s] : prev;
      float cnt = (float)(cur - prev);
      float inv = (cnt > 0.f) ? 1.f / cnt : 0.f;
      pooled[s * CDIM + t] = sums[s * CDIM + t] * inv;
      prev = cur;
    }
  }
  __syncthreads();

  int wv = t >> 6, l = t & 63;
  int j = (int)blockIdx.x * 4 + wv;
  int s = l >> 3, ch = l & 7;

  const float4* Wi4 = (const float4*)(W_ih + (size_t)(0 * HDIM + j) * CDIM);
  const float4* Wg4 = (const float4*)(W_ih + (size_t)(2 * HDIM + j) * CDIM);
  const float4* Wo4 = (const float4*)(W_ih + (size_t)(3 * HDIM + j) * CDIM);
  const float4* p4 = (const float4*)(pooled + s * CDIM);

  float di = 0.f, dg = 0.f, dd = 0.f;
#pragma unroll
  for (int i = 0; i < 8; ++i) {
    int c4 = ch * 8 + i;
    float4 p = p4[c4];
    float4 wi = Wi4[c4], wg = Wg4[c4], wo = Wo4[c4];
    di = fmaf(p.x, wi.x, di); di = fmaf(p.y, wi.y, di);
    di = fmaf(p.z, wi.z, di); di = fmaf(p.w, wi.w, di);
    dg = fmaf(p.x, wg.x, dg); dg = fmaf(p.y, wg.y, dg);
    dg = fmaf(p.z, wg.z, dg); dg = fmaf(p.w, wg.w, dg);
    dd = fmaf(p.x, wo.x, dd); dd = fmaf(p.y, wo.y, dd);
    dd = fmaf(p.z, wo.z, dd); dd = fmaf(p.w, wo.w, dd);
  }
#pragma unroll
  for (int m = 1; m < 8; m <<= 1) {
    di += __shfl_xor(di, m);
    dg += __shfl_xor(dg, m);
    dd += __shfl_xor(dd, m);
  }
  if (ch == 0 && s < nseg) {
    di += b_ih[j] + b_hh[j];
    dg += b_ih[2 * HDIM + j] + b_hh[2 * HDIM + j];
    dd += b_ih[3 * HDIM + j] + b_hh[3 * HDIM + j];
    float ig = 1.f / (1.f + expf(-di));
    float gg = tanhf(dg);
    float og = 1.f / (1.f + expf(-dd));
    h[(size_t)s * HDIM + j] = og * tanhf(ig * gg);
  }
}

// ---------------------------------------------------------------------------
// L2: ctx[s][col] = b_proj[col] + h[s]·W_proj[col].
// ---------------------------------------------------------------------------
__global__ __launch_bounds__(256) void ctx_kernel(
    const float* __restrict__ h, const float* __restrict__ W_proj,
    const float* __restrict__ b_proj, float* __restrict__ ctx, int nseg) {
  __shared__ float hs[MAXSEG * HDIM];
  int t = threadIdx.x;
  {
    const float4* hsrc = (const float4*)h;
    float4* hdst = (float4*)hs;
#pragma unroll
    for (int i = 0; i < 4; ++i) hdst[i * 256 + t] = hsrc[i * 256 + t];
  }
  __syncthreads();

  int wv = t >> 6, l = t & 63;
  int col = (int)blockIdx.x * 4 + wv;
  int s = l >> 3, ch = l & 7;

  const float4* Wp4 = (const float4*)(W_proj + (size_t)col * HDIM);
  const float4* h4 = (const float4*)(hs + s * HDIM);
  float acc = 0.f;
#pragma unroll
  for (int i = 0; i < 16; ++i) {
    int j4 = ch * 16 + i;
    float4 hv = h4[j4];
    float4 w = Wp4[j4];
    acc = fmaf(hv.x, w.x, acc); acc = fmaf(hv.y, w.y, acc);
    acc = fmaf(hv.z, w.z, acc); acc = fmaf(hv.w, w.w, acc);
  }
#pragma unroll
  for (int m = 1; m < 8; m <<= 1) acc += __shfl_xor(acc, m);
  if (ch == 0 && s < nseg) ctx[s * CDIM + col] = acc + b_proj[col];
}

// ---------------------------------------------------------------------------
// L3: delta[s][k] = ctx[s]·W_head[k]  (b_head already applied in pass A).
// ---------------------------------------------------------------------------
__global__ __launch_bounds__(256) void delta_kernel(
    const float* __restrict__ ctx, const float* __restrict__ W_head,
    float* __restrict__ delta, int nseg) {
  __shared__ float cs[MAXSEG * CDIM];
  int t = threadIdx.x;
  {
    const float4* csrc = (const float4*)ctx;
    float4* cdst = (float4*)cs;
#pragma unroll
    for (int i = 0; i < 2; ++i) cdst[i * 256 + t] = csrc[i * 256 + t];
  }
  __syncthreads();

  int wv = t >> 6, l = t & 63;
  int k = (int)blockIdx.x * 4 + wv;
  if (k >= KCLS) return;
  int s = l >> 3, ch = l & 7;

  const float4* Wh4 = (const float4*)(W_head + (size_t)k * CDIM);
  const float4* c4 = (const float4*)(cs + s * CDIM);
  float acc = 0.f;
#pragma unroll
  for (int i = 0; i < 8; ++i) {
    int idx = ch * 8 + i;
    float4 cv = c4[idx];
    float4 w = Wh4[idx];
    acc = fmaf(cv.x, w.x, acc); acc = fmaf(cv.y, w.y, acc);
    acc = fmaf(cv.z, w.z, acc); acc = fmaf(cv.w, w.w, acc);
  }
#pragma unroll
  for (int m = 1; m < 8; m <<= 1) acc += __shfl_xor(acc, m);
  if (ch == 0 && s < nseg) delta[s * KCLS + k] = acc;
}

// ---------------------------------------------------------------------------
// Pass C: out[r][k] += delta[seg(r)][k], float4 grid-stride.
// ---------------------------------------------------------------------------
__global__ __launch_bounds__(256) void add_delta_kernel(
    float* __restrict__ out, const int* __restrict__ offset,
    const float* __restrict__ delta, int n, int nseg) {
  __shared__ float dl[MAXSEG * KCLS];
  int t = threadIdx.x;
  if (t < MAXSEG * KCLS) dl[t] = (t < nseg * KCLS) ? delta[t] : 0.f;
  __syncthreads();

  int off[MAXSEG];
#pragma unroll
  for (int q = 0; q < MAXSEG; ++q) off[q] = (q < nseg) ? offset[q] : 0x7fffffff;

  long tot = (long)n * (KCLS / 4);
  long stride = (long)gridDim.x * 256;
  for (long e4 = (long)blockIdx.x * 256 + t; e4 < tot; e4 += stride) {
    long row = e4 / 5;
    int k0 = (int)(e4 - row * 5) * 4;
    int s = 0;
#pragma unroll
    for (int q = 0; q < MAXSEG - 1; ++q) s += (row >= off[q]) ? 1 : 0;
    float4 v = ((float4*)out)[e4];
    const float* d = &dl[s * KCLS + k0];
    v.x += d[0]; v.y += d[1]; v.z += d[2]; v.w += d[3];
    ((float4*)out)[e4] = v;
  }
}

extern "C" void kernel_launch(void* const* d_in, const int* in_sizes, int n_in,
                              void* d_out, int out_size, void* d_ws, size_t ws_size,
                              hipStream_t stream) {
  const float* feat   = (const float*)d_in[0];
  const int*   offset = (const int*)d_in[1];
  const float* W_ih   = (const float*)d_in[2];
  const float* b_ih   = (const float*)d_in[3];
  // d_in[4] = W_hh : unused (h0 == 0)
  const float* b_hh   = (const float*)d_in[5];
  const float* W_proj = (const float*)d_in[6];
  const float* b_proj = (const float*)d_in[7];
  const float* W_head = (const float*)d_in[8];
  const float* b_head = (const float*)d_in[9];
  float* out = (float*)d_out;

  int n = in_sizes[0] / CDIM;
  int nseg = in_sizes[1];
  if (nseg > MAXSEG) nseg = MAXSEG;

  float* ws    = (float*)d_ws;
  float* sums  = ws;                                    // 8*256
  float* h     = ws + MAXSEG * CDIM;                    // 8*512
  float* ctx   = ws + MAXSEG * CDIM + MAXSEG * HDIM;    // 8*256
  float* delta = ctx + MAXSEG * CDIM;                   // 8*20

  hipMemsetAsync(sums, 0, MAXSEG * CDIM * sizeof(float), stream);
  fused_pool_head_kernel<<<GRIDA, NTHR, 0, stream>>>(feat, offset, W_head, b_head,
                                                     sums, out, n, nseg);
  lstm_h_kernel<<<128, 256, 0, stream>>>(sums, offset, W_ih, b_ih, b_hh, h, nseg);
  ctx_kernel<<<64, 256, 0, stream>>>(h, W_proj, b_proj, ctx, nseg);
  delta_kernel<<<5, 256, 0, stream>>>(ctx, W_head, delta, nseg);
  add_delta_kernel<<<2560, 256, 0, stream>>>(out, offset, delta, n, nseg);
}

// Round 14
// 4596.323 us; speedup vs baseline: 1.1221x; 1.1221x over previous
//
#include <hip/hip_runtime.h>
#include <math.h>

#define CDIM 256
#define HDIM 512
#define KCLS 20
#define MAXSEG 8
#define TILE_R 64
#define NTHR 512
#define GRIDA 512
#define F4_TILE (TILE_R * CDIM / 4)   // 4096 fp32-float4 per tile
#define G16_TILE (F4_TILE / 2)        // 2048 bf16 16B-granules per tile

typedef __attribute__((ext_vector_type(8))) short bf16x8;
typedef __attribute__((ext_vector_type(4))) float f32x4;

// fp32 -> bf16 round-to-nearest-even (finite inputs)
__device__ __forceinline__ unsigned short f2bf(float x) {
  unsigned u = __float_as_uint(x);
  unsigned r = u + 0x7FFFu + ((u >> 16) & 1u);
  return (unsigned short)(r >> 16);
}
__device__ __forceinline__ unsigned pk2(float a, float b) {
  return (unsigned)f2bf(a) | ((unsigned)f2bf(b) << 16);
}

// Raw barrier: order LDS (lgkmcnt) but leave global loads (vmcnt) IN FLIGHT.
#define BARRIER_LDS_ONLY()                                   \
  do {                                                       \
    asm volatile("s_waitcnt lgkmcnt(0)" ::: "memory");       \
    __builtin_amdgcn_s_barrier();                            \
    __builtin_amdgcn_sched_barrier(0);                       \
  } while (0)

// ---------------------------------------------------------------------------
// Pass A: single read of feat. R8 skeleton (single LDS buffer, lgkm-only
// barriers, 2 blocks/CU) with the head moved to the MATRIX pipe:
//   tile: 64 rows x 256 cols bf16 = 32 KB, 16B-granule swizzle g^(row&7).
//   wlds: W_head padded to [32][256] bf16 = 16 KB, same swizzle (built once).
//   Every wave: staging (pair-dense coalesced loads, 1-deep, 32 VGPRs) +
//     one 16x16 MFMA unit (mt=wv&3, nt=wv>>2; 8 x mfma_f32_16x16x32_bf16,
//     layouts verified by R12's pass) + colsum of an 8-row band (uint4
//     granule reads at the b128 structural floor, fp32 accumulate,
//     flush-on-segment-change atomics).
// VGPR budget: stg 32 + acc 4 + colacc 8 + misc ~40 => ~100 < 128 cap
// (__launch_bounds__(512,4)) -> NO SPILL (R13 lesson).
// ---------------------------------------------------------------------------
__global__ __launch_bounds__(NTHR, 4) void fused_pool_head_kernel(
    const float* __restrict__ feat, const int* __restrict__ offset,
    const float* __restrict__ W_head, const float* __restrict__ b_head,
    float* __restrict__ sums, float* __restrict__ out, int n, int nseg) {
  __shared__ char tile[TILE_R * CDIM * 2];  // 32 KB bf16 feat tile
  __shared__ char wlds[32 * CDIM * 2];      // 16 KB bf16 W_head (rows 20-31=0)
  int t = threadIdx.x;
  int lane = t & 63;
  int wv = t >> 6;

  int ntiles = (n + TILE_R - 1) / TILE_R;
  int nb = (int)gridDim.x;
  int t0 = (int)blockIdx.x;
  if (t0 >= ntiles) return;

  int off[MAXSEG];
#pragma unroll
  for (int q = 0; q < MAXSEG; ++q) off[q] = (q < nseg) ? offset[q] : 0x7fffffff;

  // ---- build W_lds once: [32][256] bf16, granule-swizzled ----
#pragma unroll
  for (int i = 0; i < 4; ++i) {
    int w8 = i * NTHR + t;            // 8B granule, 0..2047
    int row = w8 >> 6, col8 = w8 & 63;
    uint2 v;
    if (row < KCLS) {
      float4 w = *(const float4*)(W_head + (size_t)row * CDIM + col8 * 4);
      v.x = pk2(w.x, w.y);
      v.y = pk2(w.z, w.w);
    } else {
      v.x = 0u; v.y = 0u;
    }
    *(uint2*)(wlds + row * 512 + (col8 ^ ((row & 7) << 1)) * 8) = v;
  }

  // ---- MFMA unit mapping: 8 units = 4 mt x 2 nt ----
  int mt = wv & 3, nt = wv >> 2;
  int arow = mt * 16 + (lane & 15);
  int brow = nt * 16 + (lane & 15);
  int kg = lane >> 4;
  int ocol = nt * 16 + (lane & 15);
  float bh = (ocol < KCLS) ? b_head[ocol] : 0.f;

  // ---- colsum mapping: band rows wv*8..wv*8+7; lane = (h=lane>>5, g) ----
  int h = lane >> 5, g = lane & 31;   // granule g covers cols g*8..g*8+7
  f32x4 ca0 = {0.f, 0.f, 0.f, 0.f}, ca1 = {0.f, 0.f, 0.f, 0.f};
  int cur_seg = -1;

  const float4* src = (const float4*)feat;
  long lim = (long)n * (CDIM / 4);
  float4 stg[8];                      // 1-deep staging, 32 VGPRs

  auto flush = [&]() {
    if (cur_seg >= 0) {
      float* d = &sums[cur_seg * CDIM + g * 8];
      atomicAdd(d + 0, ca0[0]); atomicAdd(d + 1, ca0[1]);
      atomicAdd(d + 2, ca0[2]); atomicAdd(d + 3, ca0[3]);
      atomicAdd(d + 4, ca1[0]); atomicAdd(d + 5, ca1[1]);
      atomicAdd(d + 6, ca1[2]); atomicAdd(d + 7, ca1[3]);
      ca0 = (f32x4){0.f, 0.f, 0.f, 0.f};
      ca1 = (f32x4){0.f, 0.f, 0.f, 0.f};
    }
  };

  // pair-dense loads: granule g16 = i*512+t -> f4 pair (2*g16, 2*g16+1).
  // Per instruction lanes stride 32B; the pair covers the 2KB window fully.
  auto issue = [&](int tl) {
    long base = (long)tl * F4_TILE;
    if (base + F4_TILE <= lim) {
#pragma unroll
      for (int i = 0; i < 4; ++i) {
        long p = base + (long)(i * NTHR + t) * 2;
        stg[2 * i]     = src[p];
        stg[2 * i + 1] = src[p + 1];
      }
    } else {
#pragma unroll
      for (int i = 0; i < 4; ++i) {
        long p = base + (long)(i * NTHR + t) * 2;
        stg[2 * i]     = (p < lim)     ? src[p]     : make_float4(0.f, 0.f, 0.f, 0.f);
        stg[2 * i + 1] = (p + 1 < lim) ? src[p + 1] : make_float4(0.f, 0.f, 0.f, 0.f);
      }
    }
  };
  auto dswrite = [&]() {
#pragma unroll
    for (int i = 0; i < 4; ++i) {
      int g16 = i * NTHR + t;
      int row = g16 >> 5, gin = g16 & 31;
      uint4 w;
      w.x = pk2(stg[2 * i].x,     stg[2 * i].y);
      w.y = pk2(stg[2 * i].z,     stg[2 * i].w);
      w.z = pk2(stg[2 * i + 1].x, stg[2 * i + 1].y);
      w.w = pk2(stg[2 * i + 1].z, stg[2 * i + 1].w);
      *(uint4*)(tile + row * 512 + ((gin ^ (row & 7)) << 4)) = w;
    }
  };

  auto unpack_acc = [&](uint4 u) {
    ca0[0] += __uint_as_float(u.x << 16);
    ca0[1] += __uint_as_float(u.x & 0xffff0000u);
    ca0[2] += __uint_as_float(u.y << 16);
    ca0[3] += __uint_as_float(u.y & 0xffff0000u);
    ca1[0] += __uint_as_float(u.z << 16);
    ca1[1] += __uint_as_float(u.z & 0xffff0000u);
    ca1[2] += __uint_as_float(u.w << 16);
    ca1[3] += __uint_as_float(u.w & 0xffff0000u);
  };

  auto compute = [&](int tl) {
    long r0 = (long)tl * TILE_R;
    int rows = (int)(((long)n - r0) < TILE_R ? ((long)n - r0) : TILE_R);

    // ---- MFMA head: one 16x16 unit per wave ----
    {
      f32x4 acc = {0.f, 0.f, 0.f, 0.f};
#pragma unroll
      for (int ks = 0; ks < 8; ++ks) {
        int gk = ks * 4 + kg;
        bf16x8 a = *(const bf16x8*)(tile + arow * 512 + ((gk ^ (arow & 7)) << 4));
        bf16x8 b = *(const bf16x8*)(wlds + brow * 512 + ((gk ^ (brow & 7)) << 4));
        acc = __builtin_amdgcn_mfma_f32_16x16x32_bf16(a, b, acc, 0, 0, 0);
      }
      if (ocol < KCLS) {
#pragma unroll
        for (int j = 0; j < 4; ++j) {
          int rloc = mt * 16 + kg * 4 + j;
          if (rloc < rows)
            out[(r0 + rloc) * KCLS + ocol] = acc[j] + bh;
        }
      }
    }

    // ---- colsum: 8-row band, 2 rows per read step (h splits parity) ----
    {
      int rlo = wv * 8, rhi = rlo + 8;
      if (rhi > rows) rhi = rows;
      if (rlo < rhi) {
        long ra = r0 + rlo, rb = r0 + rhi - 1;
        int s0 = 0, s1 = 0;
#pragma unroll
        for (int q = 0; q < MAXSEG - 1; ++q) {
          s0 += (ra >= off[q]) ? 1 : 0;
          s1 += (rb >= off[q]) ? 1 : 0;
        }
        if (s0 == s1) {
          if (s0 != cur_seg) { flush(); cur_seg = s0; }
#pragma unroll
          for (int i = 0; i < 4; ++i) {
            int rr = rlo + 2 * i + h;
            if (rr < rhi)
              unpack_acc(*(const uint4*)(tile + rr * 512 + ((g ^ (rr & 7)) << 4)));
          }
        } else {
          for (int i = 0; i < 4; ++i) {
            int rr = rlo + 2 * i + h;
            if (rr < rhi) {
              long r = r0 + rr;
              int s = 0;
#pragma unroll
              for (int q = 0; q < MAXSEG - 1; ++q) s += (r >= off[q]) ? 1 : 0;
              if (s != cur_seg) { flush(); cur_seg = s; }
              unpack_acc(*(const uint4*)(tile + rr * 512 + ((g ^ (rr & 7)) << 4)));
            }
          }
        }
      }
    }
  };

  // ---- prologue: stage t0, write, barrier (covers wlds too) ----
  issue(t0);
  dswrite();                          // auto vmcnt wait on t0's loads
  BARRIER_LDS_ONLY();

  for (int tl = t0; tl < ntiles; tl += nb) {
    int nxt = tl + nb;
    if (nxt < ntiles) issue(nxt);     // loads fly during compute
    compute(tl);
    BARRIER_LDS_ONLY();               // readers done (no vmcnt drain)
    if (nxt < ntiles) {
      dswrite();                      // auto vmcnt wait (issued ~compute ago)
      BARRIER_LDS_ONLY();             // writes visible
    }
  }
  flush();
}

// ---------------------------------------------------------------------------
// L1: h[s][j], wave-task = gate column j; coalesced W_ih float4 rows;
// 3-step shfl_xor reduce within 8-lane seg groups.
// ---------------------------------------------------------------------------
__global__ __launch_bounds__(256) void lstm_h_kernel(
    const float* __restrict__ sums, const int* __restrict__ offset,
    const float* __restrict__ W_ih, const float* __restrict__ b_ih,
    const float* __restrict__ b_hh, float* __restrict__ h, int nseg) {
  __shared__ float pooled[MAXSEG * CDIM];
  int t = threadIdx.x;
  {
    int prev = 0;
    for (int s = 0; s < MAXSEG; ++s) {
      int cur = (s < nseg) ? offset[s] : prev;
      float cnt = (float)(cur - prev);
      float inv = (cnt > 0.f) ? 1.f / cnt : 0.f;
      pooled[s * CDIM + t] = sums[s * CDIM + t] * inv;
      prev = cur;
    }
  }
  __syncthreads();

  int wv = t >> 6, l = t & 63;
  int j = (int)blockIdx.x * 4 + wv;
  int s = l >> 3, ch = l & 7;

  const float4* Wi4 = (const float4*)(W_ih + (size_t)(0 * HDIM + j) * CDIM);
  const float4* Wg4 = (const float4*)(W_ih + (size_t)(2 * HDIM + j) * CDIM);
  const float4* Wo4 = (const float4*)(W_ih + (size_t)(3 * HDIM + j) * CDIM);
  const float4* p4 = (const float4*)(pooled + s * CDIM);

  float di = 0.f, dg = 0.f, dd = 0.f;
#pragma unroll
  for (int i = 0; i < 8; ++i) {
    int c4 = ch * 8 + i;
    float4 p = p4[c4];
    float4 wi = Wi4[c4], wg = Wg4[c4], wo = Wo4[c4];
    di = fmaf(p.x, wi.x, di); di = fmaf(p.y, wi.y, di);
    di = fmaf(p.z, wi.z, di); di = fmaf(p.w, wi.w, di);
    dg = fmaf(p.x, wg.x, dg); dg = fmaf(p.y, wg.y, dg);
    dg = fmaf(p.z, wg.z, dg); dg = fmaf(p.w, wg.w, dg);
    dd = fmaf(p.x, wo.x, dd); dd = fmaf(p.y, wo.y, dd);
    dd = fmaf(p.z, wo.z, dd); dd = fmaf(p.w, wo.w, dd);
  }
#pragma unroll
  for (int m = 1; m < 8; m <<= 1) {
    di += __shfl_xor(di, m);
    dg += __shfl_xor(dg, m);
    dd += __shfl_xor(dd, m);
  }
  if (ch == 0 && s < nseg) {
    di += b_ih[j] + b_hh[j];
    dg += b_ih[2 * HDIM + j] + b_hh[2 * HDIM + j];
    dd += b_ih[3 * HDIM + j] + b_hh[3 * HDIM + j];
    float ig = 1.f / (1.f + expf(-di));
    float gg = tanhf(dg);
    float og = 1.f / (1.f + expf(-dd));
    h[(size_t)s * HDIM + j] = og * tanhf(ig * gg);
  }
}

// ---------------------------------------------------------------------------
// L2: ctx[s][col] = b_proj[col] + h[s]·W_proj[col].
// ---------------------------------------------------------------------------
__global__ __launch_bounds__(256) void ctx_kernel(
    const float* __restrict__ h, const float* __restrict__ W_proj,
    const float* __restrict__ b_proj, float* __restrict__ ctx, int nseg) {
  __shared__ float hs[MAXSEG * HDIM];
  int t = threadIdx.x;
  {
    const float4* hsrc = (const float4*)h;
    float4* hdst = (float4*)hs;
#pragma unroll
    for (int i = 0; i < 4; ++i) hdst[i * 256 + t] = hsrc[i * 256 + t];
  }
  __syncthreads();

  int wv = t >> 6, l = t & 63;
  int col = (int)blockIdx.x * 4 + wv;
  int s = l >> 3, ch = l & 7;

  const float4* Wp4 = (const float4*)(W_proj + (size_t)col * HDIM);
  const float4* h4 = (const float4*)(hs + s * HDIM);
  float acc = 0.f;
#pragma unroll
  for (int i = 0; i < 16; ++i) {
    int j4 = ch * 16 + i;
    float4 hv = h4[j4];
    float4 w = Wp4[j4];
    acc = fmaf(hv.x, w.x, acc); acc = fmaf(hv.y, w.y, acc);
    acc = fmaf(hv.z, w.z, acc); acc = fmaf(hv.w, w.w, acc);
  }
#pragma unroll
  for (int m = 1; m < 8; m <<= 1) acc += __shfl_xor(acc, m);
  if (ch == 0 && s < nseg) ctx[s * CDIM + col] = acc + b_proj[col];
}

// ---------------------------------------------------------------------------
// L3: delta[s][k] = ctx[s]·W_head[k]  (b_head already applied in pass A).
// ---------------------------------------------------------------------------
__global__ __launch_bounds__(256) void delta_kernel(
    const float* __restrict__ ctx, const float* __restrict__ W_head,
    float* __restrict__ delta, int nseg) {
  __shared__ float cs[MAXSEG * CDIM];
  int t = threadIdx.x;
  {
    const float4* csrc = (const float4*)ctx;
    float4* cdst = (float4*)cs;
#pragma unroll
    for (int i = 0; i < 2; ++i) cdst[i * 256 + t] = csrc[i * 256 + t];
  }
  __syncthreads();

  int wv = t >> 6, l = t & 63;
  int k = (int)blockIdx.x * 4 + wv;
  if (k >= KCLS) return;
  int s = l >> 3, ch = l & 7;

  const float4* Wh4 = (const float4*)(W_head + (size_t)k * CDIM);
  const float4* c4 = (const float4*)(cs + s * CDIM);
  float acc = 0.f;
#pragma unroll
  for (int i = 0; i < 8; ++i) {
    int idx = ch * 8 + i;
    float4 cv = c4[idx];
    float4 w = Wh4[idx];
    acc = fmaf(cv.x, w.x, acc); acc = fmaf(cv.y, w.y, acc);
    acc = fmaf(cv.z, w.z, acc); acc = fmaf(cv.w, w.w, acc);
  }
#pragma unroll
  for (int m = 1; m < 8; m <<= 1) acc += __shfl_xor(acc, m);
  if (ch == 0 && s < nseg) delta[s * KCLS + k] = acc;
}

// ---------------------------------------------------------------------------
// Pass C: out[r][k] += delta[seg(r)][k], float4 grid-stride.
// ---------------------------------------------------------------------------
__global__ __launch_bounds__(256) void add_delta_kernel(
    float* __restrict__ out, const int* __restrict__ offset,
    const float* __restrict__ delta, int n, int nseg) {
  __shared__ float dl[MAXSEG * KCLS];
  int t = threadIdx.x;
  if (t < MAXSEG * KCLS) dl[t] = (t < nseg * KCLS) ? delta[t] : 0.f;
  __syncthreads();

  int off[MAXSEG];
#pragma unroll
  for (int q = 0; q < MAXSEG; ++q) off[q] = (q < nseg) ? offset[q] : 0x7fffffff;

  long tot = (long)n * (KCLS / 4);
  long stride = (long)gridDim.x * 256;
  for (long e4 = (long)blockIdx.x * 256 + t; e4 < tot; e4 += stride) {
    long row = e4 / 5;
    int k0 = (int)(e4 - row * 5) * 4;
    int s = 0;
#pragma unroll
    for (int q = 0; q < MAXSEG - 1; ++q) s += (row >= off[q]) ? 1 : 0;
    float4 v = ((float4*)out)[e4];
    const float* d = &dl[s * KCLS + k0];
    v.x += d[0]; v.y += d[1]; v.z += d[2]; v.w += d[3];
    ((float4*)out)[e4] = v;
  }
}

extern "C" void kernel_launch(void* const* d_in, const int* in_sizes, int n_in,
                              void* d_out, int out_size, void* d_ws, size_t ws_size,
                              hipStream_t stream) {
  const float* feat   = (const float*)d_in[0];
  const int*   offset = (const int*)d_in[1];
  const float* W_ih   = (const float*)d_in[2];
  const float* b_ih   = (const float*)d_in[3];
  // d_in[4] = W_hh : unused (h0 == 0)
  const float* b_hh   = (const float*)d_in[5];
  const float* W_proj = (const float*)d_in[6];
  const float* b_proj = (const float*)d_in[7];
  const float* W_head = (const float*)d_in[8];
  const float* b_head = (const float*)d_in[9];
  float* out = (float*)d_out;

  int n = in_sizes[0] / CDIM;
  int nseg = in_sizes[1];
  if (nseg > MAXSEG) nseg = MAXSEG;

  float* ws    = (float*)d_ws;
  float* sums  = ws;                                    // 8*256
  float* h     = ws + MAXSEG * CDIM;                    // 8*512
  float* ctx   = ws + MAXSEG * CDIM + MAXSEG * HDIM;    // 8*256
  float* delta = ctx + MAXSEG * CDIM;                   // 8*20

  hipMemsetAsync(sums, 0, MAXSEG * CDIM * sizeof(float), stream);
  fused_pool_head_kernel<<<GRIDA, NTHR, 0, stream>>>(feat, offset, W_head, b_head,
                                                     sums, out, n, nseg);
  lstm_h_kernel<<<128, 256, 0, stream>>>(sums, offset, W_ih, b_ih, b_hh, h, nseg);
  ctx_kernel<<<64, 256, 0, stream>>>(h, W_proj, b_proj, ctx, nseg);
  delta_kernel<<<5, 256, 0, stream>>>(ctx, W_head, delta, nseg);
  add_delta_kernel<<<2560, 256, 0, stream>>>(out, offset, delta, n, nseg);
}